// Round 12
// baseline (282.452 us; speedup 1.0000x reference)
//
#include <hip/hip_runtime.h>
#include <hip/hip_fp16.h>

#define BB 512
#define NN 256
#define SS 128
#define MM 64
#define UNFOLDS 6

static constexpr float EPS_ = 1e-8f;
static constexpr float L2E = 1.4426950408889634f;

// ---- prep ----
// Recurrent params 6 B/entry, octet-packed: PQ6[(o*3+t)*NN + j] (float4)
//   t=0: half2 {a,c} rows 8o..8o+3 ; t=1: rows 8o+4..8o+7 ; t=2: 8x half wE
// Sensory keeps R6 pair format in SQ (f32 wE), used once.
// gate = 1/(1+exp2(a*v + c)); a = -sigma*log2e; c = sigma*mu*log2e
__global__ __launch_bounds__(256) void prep_pack6(
    const float* __restrict__ w, const float* __restrict__ sg,
    const float* __restrict__ mu, const float* __restrict__ E,
    const float* __restrict__ mask,
    const float* __restrict__ sw, const float* __restrict__ ssg,
    const float* __restrict__ smu, const float* __restrict__ sE,
    const float* __restrict__ smask,
    const float* __restrict__ iw, const float* __restrict__ ib,
    float4* __restrict__ PQ6, float4* __restrict__ SQ) {
  int idx = blockIdx.x * 256 + threadIdx.x;
  const int NP = (NN / 2) * NN;          // 32768 recurrent i-pairs
  if (idx < NP) {
    int ip = idx >> 8, j = idx & 255;
    int g0 = (2 * ip) * NN + j, g1 = g0 + NN;
    float a0 = sg[g0] * L2E, a1 = sg[g1] * L2E;
    union { __half2 h; float f; } c0, c1, cw;
    c0.h = __floats2half2_rn(-a0, a0 * mu[g0]);
    c1.h = __floats2half2_rn(-a1, a1 * mu[g1]);
    cw.h = __halves2half2(__float2half_rn(w[g0] * mask[g0] * E[g0]),
                          __float2half_rn(w[g1] * mask[g1] * E[g1]));
    int o = ip >> 2, q = ip & 3;
    float2* acdst = (float2*)(PQ6 + (o * 3 + (q >> 1)) * NN + j);
    acdst[q & 1] = make_float2(c0.f, c1.f);
    ((float*)(PQ6 + (o * 3 + 2) * NN + j))[q] = cw.f;
  } else {
    int e = idx - NP;                    // sensory entry < SS*NN
    int s = e >> 8, j = e & 255;
    float a = ssg[e] * L2E;
    union { __half2 h; float f; } u_;
    u_.h = __floats2half2_rn(-a * iw[s], a * (smu[e] - ib[s]));
    float wE = sw[e] * smask[e] * sE[e];
    float* dst = (float*)(SQ + (s >> 1) * NN + j);
    dst[(s & 1) * 2 + 0] = u_.f;
    dst[(s & 1) * 2 + 1] = wE;
  }
}

// 4 gates from one float4 sensory param (2 entries, f32 wE) + float4 of v
#define GATE4(pq, vv) do { \
  union { float f; __half2 h; } _u0, _u1; \
  _u0.f = (pq).x; _u1.f = (pq).z; \
  float2 ac0 = __half22float2(_u0.h); \
  float2 ac1 = __half22float2(_u1.h); \
  float g0a = __builtin_amdgcn_rcpf(1.f + __builtin_amdgcn_exp2f(fmaf(ac0.x, (vv).x, ac0.y))); \
  float g0b = __builtin_amdgcn_rcpf(1.f + __builtin_amdgcn_exp2f(fmaf(ac0.x, (vv).y, ac0.y))); \
  float g1a = __builtin_amdgcn_rcpf(1.f + __builtin_amdgcn_exp2f(fmaf(ac1.x, (vv).z, ac1.y))); \
  float g1b = __builtin_amdgcn_rcpf(1.f + __builtin_amdgcn_exp2f(fmaf(ac1.x, (vv).w, ac1.y))); \
  n0 = fmaf((pq).y, g0a, n0); d0 = fmaf(__builtin_fabsf((pq).y), g0a, d0); \
  n1 = fmaf((pq).y, g0b, n1); d1 = fmaf(__builtin_fabsf((pq).y), g0b, d1); \
  n0 = fmaf((pq).w, g1a, n0); d0 = fmaf(__builtin_fabsf((pq).w), g1a, d0); \
  n1 = fmaf((pq).w, g1b, n1); d1 = fmaf(__builtin_fabsf((pq).w), g1b, d1); \
} while (0)

// 4 gates from 2 packed rows: aclo/achi = half2 ac (bitcast), wfw = half2 wE
#define GPAIR(aclo, achi, wfw, vv) do { \
  union { float f; __half2 h; } _ua, _ub, _uw; \
  _ua.f = (aclo); _ub.f = (achi); _uw.f = (wfw); \
  float2 aca = __half22float2(_ua.h); \
  float2 acb = __half22float2(_ub.h); \
  float2 wf  = __half22float2(_uw.h); \
  float g0a = __builtin_amdgcn_rcpf(1.f + __builtin_amdgcn_exp2f(fmaf(aca.x, (vv).x, aca.y))); \
  float g0b = __builtin_amdgcn_rcpf(1.f + __builtin_amdgcn_exp2f(fmaf(aca.x, (vv).y, aca.y))); \
  float g1a = __builtin_amdgcn_rcpf(1.f + __builtin_amdgcn_exp2f(fmaf(acb.x, (vv).z, acb.y))); \
  float g1b = __builtin_amdgcn_rcpf(1.f + __builtin_amdgcn_exp2f(fmaf(acb.x, (vv).w, acb.y))); \
  n0 = fmaf(wf.x, g0a, n0); d0 = fmaf(__builtin_fabsf(wf.x), g0a, d0); \
  n1 = fmaf(wf.x, g0b, n1); d1 = fmaf(__builtin_fabsf(wf.x), g0b, d1); \
  n0 = fmaf(wf.y, g1a, n0); d0 = fmaf(__builtin_fabsf(wf.y), g1a, d0); \
  n1 = fmaf(wf.y, g1b, n1); d1 = fmaf(__builtin_fabsf(wf.y), g1b, d1); \
} while (0)

// async global->LDS, 16 B per lane, dest = ldsbase + lane*16
__device__ __forceinline__ void gll16(const float4* g, float4* l) {
  __builtin_amdgcn_global_load_lds(
      (const __attribute__((address_space(1))) void*)g,
      (__attribute__((address_space(3))) void*)l, 16, 0, 0);
}

// issue one octet-group (3 chunks) into stage slot g&1
#define ISSUE_GRP(g) do { \
  gll16(Pb + ((g) * 3 + 0) * NN, sb + (((g) & 1) * 3 + 0) * 64); \
  gll16(Pb + ((g) * 3 + 1) * NN, sb + (((g) & 1) * 3 + 1) * 64); \
  gll16(Pb + ((g) * 3 + 2) * NN, sb + (((g) & 1) * 3 + 2) * 64); \
} while (0)

// one block = 2 batches x all 256 columns, all unfolds; no cross-block deps.
// 1024 threads: j = tid&255 (column), split = tid>>8 (4-way over i).
// Param stream: wave-private LDS double buffer via global_load_lds; the
// stream is identical every unfold -> next unfold's prologue issued early.
__global__ __launch_bounds__(1024, 4) void ltc_dense(
    const float* __restrict__ x, const float* __restrict__ state,
    const float* __restrict__ gl, const float* __restrict__ rp,
    const float* __restrict__ cap,
    const float* __restrict__ ow, const float* __restrict__ ob,
    const float4* __restrict__ PQ6, const float4* __restrict__ SQ,
    float* __restrict__ out) {
  extern __shared__ float4 lds4[];
  float4* stage = lds4;                  // 16 waves x 2 slots x 3 chunks x 64
  float4* vA  = stage + 6144;            // 128: v[i-pair]{b0,b1,b0,b1}
  float4* vB  = vA + 128;                // 128
  float4* xt  = vB + 128;                // 64
  float4* red = xt + 64;                 // 4 splits x 256 cols {n0,n1,d0,d1}
  float2* snd2 = (float2*)(red + 1024);  // [2][256] {n,d} sensory = 256 f4 (!)

  int tid = threadIdx.x;
  int j = tid & 255;
  int split = tid >> 8;
  int wv = tid >> 6;
  int lane = tid & 63;
  int jbase = (wv & 3) * 64;
  int bbase = blockIdx.x * 2;
  float4* sb = stage + wv * 384;                       // wave-private staging
  const float4* Pb = PQ6 + (size_t)(split * 24) * NN + jbase + lane;

  if (tid < 512) {
    int b = tid >> 8, i = tid & 255;
    ((float*)vA)[(i >> 1) * 4 + (i & 1) * 2 + b] = state[(bbase + b) * NN + i];
  } else if (tid < 768) {
    int t = tid - 512, b = t >> 7, s = t & 127;
    ((float*)xt)[(s >> 1) * 4 + (s & 1) * 2 + b] = x[(bbase + b) * SS + s];
  }
  __syncthreads();

  // prologue for unfold 0 (latency hides under the sensory phase)
  ISSUE_GRP(0); ISSUE_GRP(1);

  // ---- sensory aggregation (direct loads, once) ----
  {
    float n0 = 0, n1 = 0, d0 = 0, d1 = 0;
    const float4* Sp = SQ + split * 16 * NN + j;
    const float4* xq = xt + split * 16;
#pragma unroll
    for (int c = 0; c < 16; ++c) { float4 pq = Sp[c * NN]; float4 vv = xq[c]; GATE4(pq, vv); }
    red[split * 256 + j] = make_float4(n0, n1, d0, d1);
    __syncthreads();
    if (split < 2) {
      float n = 0, dd = 0;
#pragma unroll
      for (int k = 0; k < 4; ++k) {
        float4 r = red[k * 256 + j];
        n += split ? r.y : r.x; dd += split ? r.w : r.z;
      }
      snd2[split * 256 + j] = make_float2(n, dd);
    }
    __syncthreads();
  }

  float cmt = cap[j] * (float)UNFOLDS;
  float glv = gl[j];
  float base_ = glv * rp[j];

  // ---- 6 unfolds; v ping-pongs in LDS; params DMA-staged per wave ----
  for (int u = 0; u < UNFOLDS; ++u) {
    const float4* vcur = (u & 1) ? vB : vA;
    float4* vnext = (u & 1) ? vA : vB;
    const float4* vq = vcur + split * 32;
    float n0 = 0, n1 = 0, d0 = 0, d1 = 0;
#pragma unroll
    for (int g = 0; g < 8; ++g) {
      if (g < 7) asm volatile("s_waitcnt vmcnt(3)" ::: "memory");
      else       asm volatile("s_waitcnt vmcnt(0)" ::: "memory");
      const float4* ps = sb + (g & 1) * 192;
      float4 AC0 = ps[lane];
      float4 AC1 = ps[64 + lane];
      float4 WEq = ps[128 + lane];
      float4 v01 = vq[g * 4 + 0], v23 = vq[g * 4 + 1];
      float4 v45 = vq[g * 4 + 2], v67 = vq[g * 4 + 3];
      GPAIR(AC0.x, AC0.y, WEq.x, v01);
      GPAIR(AC0.z, AC0.w, WEq.y, v23);
      GPAIR(AC1.x, AC1.y, WEq.z, v45);
      GPAIR(AC1.z, AC1.w, WEq.w, v67);
      if (g < 6) ISSUE_GRP(g + 2);
    }
    if (u < UNFOLDS - 1) { ISSUE_GRP(0); ISSUE_GRP(1); }   // next unfold, same stream
    red[split * 256 + j] = make_float4(n0, n1, d0, d1);
    __syncthreads();
    if (split < 2) {
      int b = split;
      float2 sj = snd2[b * 256 + j];
      float N = sj.x, D = sj.y;
#pragma unroll
      for (int k = 0; k < 4; ++k) {
        float4 r = red[k * 256 + j];
        N += b ? r.y : r.x; D += b ? r.w : r.z;
      }
      const float* vcf = (const float*)vcur;
      float vj = vcf[(j >> 1) * 4 + (j & 1) * 2 + b];
      float vn = (fmaf(cmt, vj, base_) + N) * __builtin_amdgcn_rcpf(cmt + glv + D + EPS_);
      ((float*)vnext)[(j >> 1) * 4 + (j & 1) * 2 + b] = vn;
      if (u == UNFOLDS - 1) {
        out[BB * MM + (bbase + b) * NN + j] = vn;
        if (j < MM) out[(bbase + b) * MM + j] = fmaf(vn, ow[j], ob[j]);
      }
    }
    __syncthreads();
  }
}

extern "C" void kernel_launch(void* const* d_in, const int* in_sizes, int n_in,
                              void* d_out, int out_size, void* d_ws, size_t ws_size,
                              hipStream_t stream) {
  const float* x     = (const float*)d_in[0];
  const float* state = (const float*)d_in[1];
  const float* gl    = (const float*)d_in[2];
  const float* rp    = (const float*)d_in[3];
  const float* cap   = (const float*)d_in[4];
  const float* w     = (const float*)d_in[5];
  const float* sg    = (const float*)d_in[6];
  const float* mu    = (const float*)d_in[7];
  const float* E     = (const float*)d_in[8];
  const float* sw    = (const float*)d_in[9];
  const float* ssg   = (const float*)d_in[10];
  const float* smu   = (const float*)d_in[11];
  const float* sE    = (const float*)d_in[12];
  const float* mask  = (const float*)d_in[13];
  const float* smask = (const float*)d_in[14];
  const float* iw    = (const float*)d_in[15];
  const float* ib    = (const float*)d_in[16];
  const float* ow    = (const float*)d_in[17];
  const float* ob    = (const float*)d_in[18];

  float4* PQ6 = (float4*)d_ws;                 // (NN/8)*3*NN f4 = 384 KiB
  float4* SQ  = PQ6 + (NN / 8) * 3 * NN;       // (SS/2)*NN f4 = 256 KiB
  float* fout = (float*)d_out;                 // [B*M out][B*N v]

  // LDS: stage 6144 + vA 128 + vB 128 + xt 64 + red 1024 + snd2 256 = 7744 f4
  const int smem = 7744 * 16;                  // 123904 B <= 160 KiB
  hipFuncSetAttribute((const void*)ltc_dense,
                      hipFuncAttributeMaxDynamicSharedMemorySize, smem);

  prep_pack6<<<((NN / 2) * NN + SS * NN) / 256, 256, 0, stream>>>(
      w, sg, mu, E, mask, sw, ssg, smu, sE, smask, iw, ib, PQ6, SQ);
  ltc_dense<<<BB / 2, 1024, smem, stream>>>(
      x, state, gl, rp, cap, ow, ob, PQ6, SQ, fout);
}

// Round 13
// 70.542 us; speedup vs baseline: 4.0040x; 4.0040x over previous
//
#include <hip/hip_runtime.h>
#include <hip/hip_fp16.h>

#define BB 512
#define NN 256
#define SS 128
#define MM 64
#define UNFOLDS 6

static constexpr float EPS_ = 1e-8f;
static constexpr float L2E = 1.4426950408889634f;

// Packed param layout (R6/R10, known-good): float4 per pair of i-entries:
//   {bitcast(half2{a_i, c_i}), wE_i, bitcast(half2{a_i1, c_i1}), wE_i1}
// gate = 1/(1+exp2(a*v + c)); a = -sigma*log2e; c = sigma*mu*log2e
__global__ __launch_bounds__(256) void prep_pack(
    const float* __restrict__ w, const float* __restrict__ sg,
    const float* __restrict__ mu, const float* __restrict__ E,
    const float* __restrict__ mask,
    const float* __restrict__ sw, const float* __restrict__ ssg,
    const float* __restrict__ smu, const float* __restrict__ sE,
    const float* __restrict__ smask,
    const float* __restrict__ iw, const float* __restrict__ ib,
    float4* __restrict__ PQ, float4* __restrict__ SQ) {
  int idx = blockIdx.x * 256 + threadIdx.x;
  union { __half2 h; float f; } u_;
  if (idx < NN * NN) {
    int i = idx >> 8, j = idx & 255;
    float a = sg[idx] * L2E;
    u_.h = __floats2half2_rn(-a, a * mu[idx]);
    float wE = w[idx] * mask[idx] * E[idx];
    float* dst = (float*)(PQ + (i >> 1) * NN + j);
    dst[(i & 1) * 2 + 0] = u_.f;
    dst[(i & 1) * 2 + 1] = wE;
  } else {
    int e = idx - NN * NN;        // < SS*NN
    int s = e >> 8, j = e & 255;
    float a = ssg[e] * L2E;
    // fold input affine: a' = -a*iw[s], c' = a*(smu - ib[s])
    u_.h = __floats2half2_rn(-a * iw[s], a * (smu[e] - ib[s]));
    float wE = sw[e] * smask[e] * sE[e];
    float* dst = (float*)(SQ + (s >> 1) * NN + j);
    dst[(s & 1) * 2 + 0] = u_.f;
    dst[(s & 1) * 2 + 1] = wE;
  }
}

// 4 gates (2 param entries x 2 batches) from one float4 param + one float4 of v
#define GATE4(pq, vv) do { \
  union { float f; __half2 h; } _u0, _u1; \
  _u0.f = (pq).x; _u1.f = (pq).z; \
  float2 ac0 = __half22float2(_u0.h); \
  float2 ac1 = __half22float2(_u1.h); \
  float g0a = __builtin_amdgcn_rcpf(1.f + __builtin_amdgcn_exp2f(fmaf(ac0.x, (vv).x, ac0.y))); \
  float g0b = __builtin_amdgcn_rcpf(1.f + __builtin_amdgcn_exp2f(fmaf(ac0.x, (vv).y, ac0.y))); \
  float g1a = __builtin_amdgcn_rcpf(1.f + __builtin_amdgcn_exp2f(fmaf(ac1.x, (vv).z, ac1.y))); \
  float g1b = __builtin_amdgcn_rcpf(1.f + __builtin_amdgcn_exp2f(fmaf(ac1.x, (vv).w, ac1.y))); \
  n0 = fmaf((pq).y, g0a, n0); d0 = fmaf(__builtin_fabsf((pq).y), g0a, d0); \
  n1 = fmaf((pq).y, g0b, n1); d1 = fmaf(__builtin_fabsf((pq).y), g0b, d1); \
  n0 = fmaf((pq).w, g1a, n0); d0 = fmaf(__builtin_fabsf((pq).w), g1a, d0); \
  n1 = fmaf((pq).w, g1b, n1); d1 = fmaf(__builtin_fabsf((pq).w), g1b, d1); \
} while (0)

// async global->LDS, 16 B per lane, dest = ldsbase + lane*16 (wave-uniform base)
__device__ __forceinline__ void gll16(const float4* g, float4* l) {
  __builtin_amdgcn_global_load_lds(
      (const __attribute__((address_space(1))) void*)g,
      (__attribute__((address_space(3))) void*)l, 16, 0, 0);
}

// issue one 2-chunk group into ring slot g&3
#define ISSUE_GRP(g) do { \
  gll16(Pb + (2 * (g) + 0) * NN, sb + (((g) & 3) * 2 + 0) * 64); \
  gll16(Pb + (2 * (g) + 1) * NN, sb + (((g) & 3) * 2 + 1) * 64); \
} while (0)

// one block = 2 batches x all 256 columns, all unfolds; no cross-block deps.
// 1024 threads: j = tid&255 (column), split = tid>>8 (4-way over i).
// Param stream staged via wave-private LDS ring buffer (global_load_lds):
// 4 slots x 2 chunks, issue g+4 while computing g -> ~3 iterations of latency
// coverage per group (R10 had 1). Same LDS total as R10; format unchanged.
__global__ __launch_bounds__(1024, 4) void ltc_dense(
    const float* __restrict__ x, const float* __restrict__ state,
    const float* __restrict__ gl, const float* __restrict__ rp,
    const float* __restrict__ cap,
    const float* __restrict__ ow, const float* __restrict__ ob,
    const float4* __restrict__ PQ, const float4* __restrict__ SQ,
    float* __restrict__ out) {
  extern __shared__ float4 lds4[];
  float4* stage = lds4;                  // 16 waves x 4 slots x 2 chunks x 64
  float4* vA  = stage + 8192;            // 128: v[i-pair]{b0,b1,b0,b1}
  float4* vB  = vA + 128;                // 128
  float4* xt  = vB + 128;                // 64
  float4* red = xt + 64;                 // 4 splits x 256 cols {n0,n1,d0,d1}
  float2* snd2 = (float2*)(red + 1024);  // [2][256] {n,d} sensory = 256 f4

  int tid = threadIdx.x;
  int j = tid & 255;
  int split = tid >> 8;
  int wv = tid >> 6;            // wave id 0..15
  int lane = tid & 63;
  int jbase = (wv & 3) * 64;    // wave's column base (j = jbase + lane)
  int bbase = blockIdx.x * 2;
  float4* sb = stage + wv * 512;                      // wave-private ring
  const float4* Pb = PQ + (size_t)(split * 32) * NN + jbase + lane;

  if (tid < 512) {
    int b = tid >> 8, i = tid & 255;
    ((float*)vA)[(i >> 1) * 4 + (i & 1) * 2 + b] = state[(bbase + b) * NN + i];
  } else if (tid < 768) {
    int t = tid - 512, b = t >> 7, s = t & 127;
    ((float*)xt)[(s >> 1) * 4 + (s & 1) * 2 + b] = x[(bbase + b) * SS + s];
  }
  __syncthreads();

  // ---- sensory aggregation (direct loads, one-time) ----
  {
    float n0 = 0, n1 = 0, d0 = 0, d1 = 0;
    const float4* Sp = SQ + split * 16 * NN + j;
    const float4* xq = xt + split * 16;
#pragma unroll
    for (int c = 0; c < 16; ++c) { float4 pq = Sp[c * NN]; float4 vv = xq[c]; GATE4(pq, vv); }
    red[split * 256 + j] = make_float4(n0, n1, d0, d1);
    __syncthreads();
    if (split < 2) {
      float n = 0, dd = 0;
#pragma unroll
      for (int k = 0; k < 4; ++k) {
        float4 r = red[k * 256 + j];
        n += split ? r.y : r.x; dd += split ? r.w : r.z;
      }
      snd2[split * 256 + j] = make_float2(n, dd);
    }
    __syncthreads();
  }

  float cmt = cap[j] * (float)UNFOLDS;
  float glv = gl[j];
  float base_ = glv * rp[j];

  // ---- 6 unfolds, v ping-pongs in LDS; params DMA-staged per wave ----
  for (int u = 0; u < UNFOLDS; ++u) {
    const float4* vcur = (u & 1) ? vB : vA;
    float4* vnext = (u & 1) ? vA : vB;
    const float4* vq = vcur + split * 32;
    float n0 = 0, n1 = 0, d0 = 0, d1 = 0;
    // prologue: fill the 4-slot ring
    ISSUE_GRP(0); ISSUE_GRP(1); ISSUE_GRP(2); ISSUE_GRP(3);
#pragma unroll
    for (int g = 0; g < 16; ++g) {
      if (g <= 12)      asm volatile("s_waitcnt vmcnt(6)" ::: "memory");
      else if (g == 13) asm volatile("s_waitcnt vmcnt(4)" ::: "memory");
      else if (g == 14) asm volatile("s_waitcnt vmcnt(2)" ::: "memory");
      else              asm volatile("s_waitcnt vmcnt(0)" ::: "memory");
      const float4* ps = sb + (g & 3) * 128;
      float4 pq0 = ps[lane];
      float4 pq1 = ps[64 + lane];
      float4 v0 = vq[g * 2 + 0], v1 = vq[g * 2 + 1];
      GATE4(pq0, v0);
      GATE4(pq1, v1);
      if (g < 12) ISSUE_GRP(g + 4);
    }
    red[split * 256 + j] = make_float4(n0, n1, d0, d1);
    __syncthreads();
    if (split < 2) {
      int b = split;
      float2 sj = snd2[b * 256 + j];
      float N = sj.x, D = sj.y;
#pragma unroll
      for (int k = 0; k < 4; ++k) {
        float4 r = red[k * 256 + j];
        N += b ? r.y : r.x; D += b ? r.w : r.z;
      }
      const float* vcf = (const float*)vcur;
      float vj = vcf[(j >> 1) * 4 + (j & 1) * 2 + b];
      float vn = (fmaf(cmt, vj, base_) + N) * __builtin_amdgcn_rcpf(cmt + glv + D + EPS_);
      ((float*)vnext)[(j >> 1) * 4 + (j & 1) * 2 + b] = vn;
      if (u == UNFOLDS - 1) {
        out[BB * MM + (bbase + b) * NN + j] = vn;
        if (j < MM) out[(bbase + b) * MM + j] = fmaf(vn, ow[j], ob[j]);
      }
    }
    __syncthreads();
  }
}

extern "C" void kernel_launch(void* const* d_in, const int* in_sizes, int n_in,
                              void* d_out, int out_size, void* d_ws, size_t ws_size,
                              hipStream_t stream) {
  const float* x     = (const float*)d_in[0];
  const float* state = (const float*)d_in[1];
  const float* gl    = (const float*)d_in[2];
  const float* rp    = (const float*)d_in[3];
  const float* cap   = (const float*)d_in[4];
  const float* w     = (const float*)d_in[5];
  const float* sg    = (const float*)d_in[6];
  const float* mu    = (const float*)d_in[7];
  const float* E     = (const float*)d_in[8];
  const float* sw    = (const float*)d_in[9];
  const float* ssg   = (const float*)d_in[10];
  const float* smu   = (const float*)d_in[11];
  const float* sE    = (const float*)d_in[12];
  const float* mask  = (const float*)d_in[13];
  const float* smask = (const float*)d_in[14];
  const float* iw    = (const float*)d_in[15];
  const float* ib    = (const float*)d_in[16];
  const float* ow    = (const float*)d_in[17];
  const float* ob    = (const float*)d_in[18];

  float4* PQ = (float4*)d_ws;                  // [NN/2][NN] = 512 KiB
  float4* SQ = PQ + (NN / 2) * NN;             // [SS/2][NN] = 256 KiB
  float* fout = (float*)d_out;                 // [B*M out][B*N v]

  // LDS: stage 8192 + vA 128 + vB 128 + xt 64 + red 1024 + snd2 256 = 9792 f4
  const int smem = 9792 * 16;                  // 156672 B <= 163840 B
  hipFuncSetAttribute((const void*)ltc_dense,
                      hipFuncAttributeMaxDynamicSharedMemorySize, smem);

  prep_pack<<<(NN * NN + SS * NN) / 256, 256, 0, stream>>>(
      w, sg, mu, E, mask, sw, ssg, smu, sE, smask, iw, ib, PQ, SQ);
  ltc_dense<<<BB / 2, 1024, smem, stream>>>(
      x, state, gl, rp, cap, ow, ob, PQ, SQ, fout);
}

// Round 14
// 57.324 us; speedup vs baseline: 4.9273x; 1.2306x over previous
//
#include <hip/hip_runtime.h>
#include <hip/hip_fp16.h>

#define BB 512
#define NN 256
#define SS 128
#define MM 64
#define UNFOLDS 6

static constexpr float EPS_ = 1e-8f;
static constexpr float L2E = 1.4426950408889634f;

// ---- prep A (blocks 0..255): column-compact recurrent params, column j=bid ----
// entry (r,j): float2 { bitcast(half2{a,c}), wE with source-idx in low 8 mantissa bits }
// packed pairwise into float4 rows PC4[r>>1][j] (R13 layout); rows >= cnt zeroed.
// ---- prep A (blocks 256..383): dense sensory pack (R13 SQ format) ----
__global__ __launch_bounds__(256) void prep_compact(
    const float* __restrict__ w, const float* __restrict__ sg,
    const float* __restrict__ mu, const float* __restrict__ E,
    const float* __restrict__ mask,
    const float* __restrict__ sw, const float* __restrict__ ssg,
    const float* __restrict__ smu, const float* __restrict__ sE,
    const float* __restrict__ smask,
    const float* __restrict__ iw, const float* __restrict__ ib,
    float2* __restrict__ PC2, int* __restrict__ cnt, float4* __restrict__ SQ) {
  int bid = blockIdx.x;
  int t = threadIdx.x;
  if (bid < 256) {
    int j = bid;
    int lane = t & 63, wvi = t >> 6;
    __shared__ int wtot[4];
    int g = t * NN + j;
    float m = mask[g];
    bool active = (m != 0.0f);
    float a = sg[g] * L2E;
    union { __half2 h; float f; } ac;
    ac.h = __floats2half2_rn(-a, a * mu[g]);
    float wE = w[g] * m * E[g];
    unsigned uw = (__float_as_uint(wE) & 0xFFFFFF00u) | (unsigned)t;
    unsigned long long bal = __ballot(active);
    if (lane == 63) wtot[wvi] = __popcll(bal);
    __syncthreads();
    int base = 0;
    for (int k = 0; k < wvi; ++k) base += wtot[k];
    int total = wtot[0] + wtot[1] + wtot[2] + wtot[3];
    if (active) {
      int r = base + __popcll(bal & ((1ull << lane) - 1ull));
      PC2[((r >> 1) * NN + j) * 2 + (r & 1)] = make_float2(ac.f, __uint_as_float(uw));
    }
    int zr = total + t;
    if (zr < 256) PC2[((zr >> 1) * NN + j) * 2 + (zr & 1)] = make_float2(0.f, 0.f);
    if (t == 0) cnt[j] = total;
  } else {
    int e = (bid - 256) * 256 + t;       // < SS*NN
    int s = e >> 8, j = e & 255;
    float a = ssg[e] * L2E;
    union { __half2 h; float f; } u_;
    u_.h = __floats2half2_rn(-a * iw[s], a * (smu[e] - ib[s]));
    float wE = sw[e] * smask[e] * sE[e];
    float* dst = (float*)(SQ + (s >> 1) * NN + j);
    dst[(s & 1) * 2 + 0] = u_.f;
    dst[(s & 1) * 2 + 1] = wE;
  }
}

// max over cnt, padded to multiple of 16
__global__ __launch_bounds__(256) void prep_kmax(const int* __restrict__ cnt,
                                                 int* __restrict__ kmax) {
  __shared__ int red[256];
  int t = threadIdx.x;
  red[t] = cnt[t];
  __syncthreads();
  for (int s2 = 128; s2 > 0; s2 >>= 1) {
    if (t < s2) red[t] = max(red[t], red[t + s2]);
    __syncthreads();
  }
  if (t == 0) *kmax = (red[0] + 15) & ~15;
}

// sensory: 4 gates from one float4 (2 entries, f32 wE) + float4 of x
#define GATE4(pq, vv) do { \
  union { float f; __half2 h; } _u0, _u1; \
  _u0.f = (pq).x; _u1.f = (pq).z; \
  float2 ac0 = __half22float2(_u0.h); \
  float2 ac1 = __half22float2(_u1.h); \
  float g0a = __builtin_amdgcn_rcpf(1.f + __builtin_amdgcn_exp2f(fmaf(ac0.x, (vv).x, ac0.y))); \
  float g0b = __builtin_amdgcn_rcpf(1.f + __builtin_amdgcn_exp2f(fmaf(ac0.x, (vv).y, ac0.y))); \
  float g1a = __builtin_amdgcn_rcpf(1.f + __builtin_amdgcn_exp2f(fmaf(ac1.x, (vv).z, ac1.y))); \
  float g1b = __builtin_amdgcn_rcpf(1.f + __builtin_amdgcn_exp2f(fmaf(ac1.x, (vv).w, ac1.y))); \
  n0 = fmaf((pq).y, g0a, n0); d0 = fmaf(__builtin_fabsf((pq).y), g0a, d0); \
  n1 = fmaf((pq).y, g0b, n1); d1 = fmaf(__builtin_fabsf((pq).y), g0b, d1); \
  n0 = fmaf((pq).w, g1a, n0); d0 = fmaf(__builtin_fabsf((pq).w), g1a, d0); \
  n1 = fmaf((pq).w, g1b, n1); d1 = fmaf(__builtin_fabsf(( pq).w), g1b, d1); \
} while (0)

// recurrent: 2 gates (1 compacted entry x 2 batches); wfr carries idx in low bits
// (treated as wE: abs perturbation ~1e-43, negligible)
#define GATEE(acf, wfr, vv) do { \
  union { float f; __half2 h; } _a; _a.f = (acf); \
  float2 ac = __half22float2(_a.h); \
  float ga = __builtin_amdgcn_rcpf(1.f + __builtin_amdgcn_exp2f(fmaf(ac.x, (vv).x, ac.y))); \
  float gb = __builtin_amdgcn_rcpf(1.f + __builtin_amdgcn_exp2f(fmaf(ac.x, (vv).y, ac.y))); \
  n0 = fmaf((wfr), ga, n0); d0 = fmaf(__builtin_fabsf(wfr), ga, d0); \
  n1 = fmaf((wfr), gb, n1); d1 = fmaf(__builtin_fabsf(wfr), gb, d1); \
} while (0)

// async global->LDS, 16 B per lane
__device__ __forceinline__ void gll16(const float4* g, float4* l) {
  __builtin_amdgcn_global_load_lds(
      (const __attribute__((address_space(1))) void*)g,
      (__attribute__((address_space(3))) void*)l, 16, 0, 0);
}

// issue one 2-chunk group (f4-rows 2g, 2g+1) into ring slot g&3
#define ISSUE_GRP(g) do { \
  gll16(Pb + (2 * (g) + 0) * NN, sb + (((g) & 3) * 2 + 0) * 64); \
  gll16(Pb + (2 * (g) + 1) * NN, sb + (((g) & 3) * 2 + 1) * 64); \
} while (0)

// one block = 2 batches x all 256 columns, all unfolds; no cross-block deps.
// Compacted param stream (kmax rows, wave-uniform), DMA ring as R13;
// v as float2[256]{b0,b1} in LDS, gathered per entry via embedded idx.
__global__ __launch_bounds__(1024, 4) void ltc_sparse(
    const float* __restrict__ x, const float* __restrict__ state,
    const float* __restrict__ gl, const float* __restrict__ rp,
    const float* __restrict__ cap,
    const float* __restrict__ ow, const float* __restrict__ ob,
    const float4* __restrict__ PC4, const float4* __restrict__ SQ,
    const int* __restrict__ kmaxp, float* __restrict__ out) {
  extern __shared__ float4 lds4[];
  float4* stage = lds4;                  // 16w x 4slot x 2chunk x 64 = 8192 f4
  float2* vA2 = (float2*)(stage + 8192); // 256 f2 (128 f4)
  float2* vB2 = vA2 + 256;               // 128 f4
  float4* xt  = (float4*)(vB2 + 256);    // 64 f4
  float4* red = xt + 64;                 // 1024 f4
  float2* snd2 = (float2*)(red + 1024);  // 256 f4

  int tid = threadIdx.x;
  int j = tid & 255;
  int split = tid >> 8;
  int wv = tid >> 6;
  int lane = tid & 63;
  int jbase = (wv & 3) * 64;
  int bbase = blockIdx.x * 2;
  float4* sb = stage + wv * 512;
  int km = *kmaxp;                       // uniform; multiple of 16, >= ~96
  int G = km >> 4;                       // groups per split (4 entries/group)
  const float4* Pb = PC4 + (size_t)(split * (km >> 3)) * NN + jbase + lane;

  if (tid < 512) {
    int b = tid >> 8, i = tid & 255;
    ((float*)vA2)[i * 2 + b] = state[(bbase + b) * NN + i];
  } else if (tid < 768) {
    int t = tid - 512, b = t >> 7, s = t & 127;
    ((float*)xt)[(s >> 1) * 4 + (s & 1) * 2 + b] = x[(bbase + b) * SS + s];
  }
  __syncthreads();

  // ---- sensory aggregation (dense, as R13) ----
  {
    float n0 = 0, n1 = 0, d0 = 0, d1 = 0;
    const float4* Sp = SQ + split * 16 * NN + j;
    const float4* xq = xt + split * 16;
#pragma unroll
    for (int c = 0; c < 16; ++c) { float4 pq = Sp[c * NN]; float4 vv = xq[c]; GATE4(pq, vv); }
    red[split * 256 + j] = make_float4(n0, n1, d0, d1);
    __syncthreads();
    if (split < 2) {
      float n = 0, dd = 0;
#pragma unroll
      for (int k = 0; k < 4; ++k) {
        float4 r = red[k * 256 + j];
        n += split ? r.y : r.x; dd += split ? r.w : r.z;
      }
      snd2[split * 256 + j] = make_float2(n, dd);
    }
    __syncthreads();
  }

  float cmt = cap[j] * (float)UNFOLDS;
  float glv = gl[j];
  float base_ = glv * rp[j];

  // ---- 6 unfolds ----
  for (int u = 0; u < UNFOLDS; ++u) {
    const float2* vt2 = (u & 1) ? vB2 : vA2;
    float* vnf = (float*)((u & 1) ? vA2 : vB2);
    float n0 = 0, n1 = 0, d0 = 0, d1 = 0;

    auto body = [&](int g) {
      const float4* ps = sb + (g & 3) * 128;
      float4 pq0 = ps[lane];
      float4 pq1 = ps[64 + lane];
      float2 va0 = vt2[__float_as_uint(pq0.y) & 0xFF];
      float2 va1 = vt2[__float_as_uint(pq0.w) & 0xFF];
      float2 va2 = vt2[__float_as_uint(pq1.y) & 0xFF];
      float2 va3 = vt2[__float_as_uint(pq1.w) & 0xFF];
      GATEE(pq0.x, pq0.y, va0);
      GATEE(pq0.z, pq0.w, va1);
      GATEE(pq1.x, pq1.y, va2);
      GATEE(pq1.z, pq1.w, va3);
    };

    ISSUE_GRP(0); ISSUE_GRP(1); ISSUE_GRP(2); ISSUE_GRP(3);
    for (int g = 0; g < G - 4; ++g) {
      asm volatile("s_waitcnt vmcnt(6)" ::: "memory");
      body(g);
      ISSUE_GRP(g + 4);
    }
    asm volatile("s_waitcnt vmcnt(6)" ::: "memory"); body(G - 4);
    asm volatile("s_waitcnt vmcnt(4)" ::: "memory"); body(G - 3);
    asm volatile("s_waitcnt vmcnt(2)" ::: "memory"); body(G - 2);
    asm volatile("s_waitcnt vmcnt(0)" ::: "memory"); body(G - 1);

    red[split * 256 + j] = make_float4(n0, n1, d0, d1);
    __syncthreads();
    if (split < 2) {
      int b = split;
      float2 sj = snd2[b * 256 + j];
      float N = sj.x, D = sj.y;
#pragma unroll
      for (int k = 0; k < 4; ++k) {
        float4 r = red[k * 256 + j];
        N += b ? r.y : r.x; D += b ? r.w : r.z;
      }
      float2 vj2 = ((const float2*)vt2)[j];
      float vj = b ? vj2.y : vj2.x;
      float vn = (fmaf(cmt, vj, base_) + N) * __builtin_amdgcn_rcpf(cmt + glv + D + EPS_);
      vnf[j * 2 + b] = vn;
      if (u == UNFOLDS - 1) {
        out[BB * MM + (bbase + b) * NN + j] = vn;
        if (j < MM) out[(bbase + b) * MM + j] = fmaf(vn, ow[j], ob[j]);
      }
    }
    __syncthreads();
  }
}

extern "C" void kernel_launch(void* const* d_in, const int* in_sizes, int n_in,
                              void* d_out, int out_size, void* d_ws, size_t ws_size,
                              hipStream_t stream) {
  const float* x     = (const float*)d_in[0];
  const float* state = (const float*)d_in[1];
  const float* gl    = (const float*)d_in[2];
  const float* rp    = (const float*)d_in[3];
  const float* cap   = (const float*)d_in[4];
  const float* w     = (const float*)d_in[5];
  const float* sg    = (const float*)d_in[6];
  const float* mu    = (const float*)d_in[7];
  const float* E     = (const float*)d_in[8];
  const float* sw    = (const float*)d_in[9];
  const float* ssg   = (const float*)d_in[10];
  const float* smu   = (const float*)d_in[11];
  const float* sE    = (const float*)d_in[12];
  const float* mask  = (const float*)d_in[13];
  const float* smask = (const float*)d_in[14];
  const float* iw    = (const float*)d_in[15];
  const float* ib    = (const float*)d_in[16];
  const float* ow    = (const float*)d_in[17];
  const float* ob    = (const float*)d_in[18];

  float4* PC4 = (float4*)d_ws;                 // [128][NN] f4 = 512 KiB
  float4* SQ  = PC4 + 128 * NN;                // [SS/2][NN] f4 = 256 KiB
  int* cnt    = (int*)(SQ + (SS / 2) * NN);    // 256 ints
  int* kmax   = cnt + 256;
  float* fout = (float*)d_out;                 // [B*M out][B*N v]

  // LDS: stage 8192 + v 256 + xt 64 + red 1024 + snd2 256 = 9792 f4
  const int smem = 9792 * 16;                  // 156672 B <= 163840 B
  hipFuncSetAttribute((const void*)ltc_sparse,
                      hipFuncAttributeMaxDynamicSharedMemorySize, smem);

  prep_compact<<<256 + (SS * NN) / 256, 256, 0, stream>>>(
      w, sg, mu, E, mask, sw, ssg, smu, sE, smask, iw, ib,
      (float2*)PC4, cnt, SQ);
  prep_kmax<<<1, 256, 0, stream>>>(cnt, kmax);
  ltc_sparse<<<BB / 2, 1024, smem, stream>>>(
      x, state, gl, rp, cap, ow, ob, PC4, SQ, kmax, fout);
}

// Round 15
// 56.516 us; speedup vs baseline: 4.9977x; 1.0143x over previous
//
#include <hip/hip_runtime.h>
#include <hip/hip_fp16.h>

#define BB 512
#define NN 256
#define SS 128
#define MM 64
#define UNFOLDS 6

static constexpr float EPS_ = 1e-8f;
static constexpr float L2E = 1.4426950408889634f;

// ---- prep A (blocks 0..255): column-compact recurrent params, column j=bid ----
// entry (r,j): float2 { bitcast(half2{a,c}), wE with source-idx in low 8 mantissa bits }
// packed pairwise into float4 rows PC4[r>>1][j]; rows >= cnt zeroed.
// ---- prep A (blocks 256..383): dense sensory pack (R13 SQ format) ----
__global__ __launch_bounds__(256) void prep_compact(
    const float* __restrict__ w, const float* __restrict__ sg,
    const float* __restrict__ mu, const float* __restrict__ E,
    const float* __restrict__ mask,
    const float* __restrict__ sw, const float* __restrict__ ssg,
    const float* __restrict__ smu, const float* __restrict__ sE,
    const float* __restrict__ smask,
    const float* __restrict__ iw, const float* __restrict__ ib,
    float2* __restrict__ PC2, int* __restrict__ cnt, float4* __restrict__ SQ) {
  int bid = blockIdx.x;
  int t = threadIdx.x;
  if (bid < 256) {
    int j = bid;
    int lane = t & 63, wvi = t >> 6;
    __shared__ int wtot[4];
    int g = t * NN + j;
    float m = mask[g];
    bool active = (m != 0.0f);
    float a = sg[g] * L2E;
    union { __half2 h; float f; } ac;
    ac.h = __floats2half2_rn(-a, a * mu[g]);
    float wE = w[g] * m * E[g];
    unsigned uw = (__float_as_uint(wE) & 0xFFFFFF00u) | (unsigned)t;
    unsigned long long bal = __ballot(active);
    if (lane == 63) wtot[wvi] = __popcll(bal);
    __syncthreads();
    int base = 0;
    for (int k = 0; k < wvi; ++k) base += wtot[k];
    int total = wtot[0] + wtot[1] + wtot[2] + wtot[3];
    if (active) {
      int r = base + __popcll(bal & ((1ull << lane) - 1ull));
      PC2[((r >> 1) * NN + j) * 2 + (r & 1)] = make_float2(ac.f, __uint_as_float(uw));
    }
    int zr = total + t;
    if (zr < 256) PC2[((zr >> 1) * NN + j) * 2 + (zr & 1)] = make_float2(0.f, 0.f);
    if (t == 0) cnt[j] = total;
  } else {
    int e = (bid - 256) * 256 + t;       // < SS*NN
    int s = e >> 8, j = e & 255;
    float a = ssg[e] * L2E;
    union { __half2 h; float f; } u_;
    u_.h = __floats2half2_rn(-a * iw[s], a * (smu[e] - ib[s]));
    float wE = sw[e] * smask[e] * sE[e];
    float* dst = (float*)(SQ + (s >> 1) * NN + j);
    dst[(s & 1) * 2 + 0] = u_.f;
    dst[(s & 1) * 2 + 1] = wE;
  }
}

// max over cnt, padded to multiple of 16
__global__ __launch_bounds__(256) void prep_kmax(const int* __restrict__ cnt,
                                                 int* __restrict__ kmax) {
  __shared__ int red[256];
  int t = threadIdx.x;
  red[t] = cnt[t];
  __syncthreads();
  for (int s2 = 128; s2 > 0; s2 >>= 1) {
    if (t < s2) red[t] = max(red[t], red[t + s2]);
    __syncthreads();
  }
  if (t == 0) *kmax = (red[0] + 15) & ~15;
}

// sensory: 4 gates from one float4 (2 entries, f32 wE) + float4 of x
#define GATE4(pq, vv) do { \
  union { float f; __half2 h; } _u0, _u1; \
  _u0.f = (pq).x; _u1.f = (pq).z; \
  float2 ac0 = __half22float2(_u0.h); \
  float2 ac1 = __half22float2(_u1.h); \
  float g0a = __builtin_amdgcn_rcpf(1.f + __builtin_amdgcn_exp2f(fmaf(ac0.x, (vv).x, ac0.y))); \
  float g0b = __builtin_amdgcn_rcpf(1.f + __builtin_amdgcn_exp2f(fmaf(ac0.x, (vv).y, ac0.y))); \
  float g1a = __builtin_amdgcn_rcpf(1.f + __builtin_amdgcn_exp2f(fmaf(ac1.x, (vv).z, ac1.y))); \
  float g1b = __builtin_amdgcn_rcpf(1.f + __builtin_amdgcn_exp2f(fmaf(ac1.x, (vv).w, ac1.y))); \
  n0 = fmaf((pq).y, g0a, n0); d0 = fmaf(__builtin_fabsf((pq).y), g0a, d0); \
  n1 = fmaf((pq).y, g0b, n1); d1 = fmaf(__builtin_fabsf((pq).y), g0b, d1); \
  n0 = fmaf((pq).w, g1a, n0); d0 = fmaf(__builtin_fabsf((pq).w), g1a, d0); \
  n1 = fmaf((pq).w, g1b, n1); d1 = fmaf(__builtin_fabsf((pq).w), g1b, d1); \
} while (0)

// recurrent: 2 gates (1 compacted entry x 2 batches); wfr carries idx in low bits
#define GATEE(acf, wfr, vv) do { \
  union { float f; __half2 h; } _a; _a.f = (acf); \
  float2 ac = __half22float2(_a.h); \
  float ga = __builtin_amdgcn_rcpf(1.f + __builtin_amdgcn_exp2f(fmaf(ac.x, (vv).x, ac.y))); \
  float gb = __builtin_amdgcn_rcpf(1.f + __builtin_amdgcn_exp2f(fmaf(ac.x, (vv).y, ac.y))); \
  n0 = fmaf((wfr), ga, n0); d0 = fmaf(__builtin_fabsf(wfr), ga, d0); \
  n1 = fmaf((wfr), gb, n1); d1 = fmaf(__builtin_fabsf(wfr), gb, d1); \
} while (0)

// async global->LDS, 16 B per lane
__device__ __forceinline__ void gll16(const float4* g, float4* l) {
  __builtin_amdgcn_global_load_lds(
      (const __attribute__((address_space(1))) void*)g,
      (__attribute__((address_space(3))) void*)l, 16, 0, 0);
}

// one block = 2 batches x all 256 columns, all unfolds; no cross-block deps.
// Compacted param stream (kmax rows, wave-uniform), wave-private LDS DMA ring.
// NEW (T3/T4): global group counter across all 6 unfolds -- ring slots continue,
// vmcnt never drains mid-stream (single 6/4/2/0 ladder at the very end);
// barriers are raw lgkmcnt(0)+s_barrier so DMA stays in flight across them.
__global__ __launch_bounds__(1024, 4) void ltc_sparse(
    const float* __restrict__ x, const float* __restrict__ state,
    const float* __restrict__ gl, const float* __restrict__ rp,
    const float* __restrict__ cap,
    const float* __restrict__ ow, const float* __restrict__ ob,
    const float4* __restrict__ PC4, const float4* __restrict__ SQ,
    const int* __restrict__ kmaxp, float* __restrict__ out) {
  extern __shared__ float4 lds4[];
  float4* stage = lds4;                  // 16w x 4slot x 2chunk x 64 = 8192 f4
  float2* vA2 = (float2*)(stage + 8192); // 256 f2 (128 f4)
  float2* vB2 = vA2 + 256;               // 128 f4
  float4* xt  = (float4*)(vB2 + 256);    // 64 f4
  float4* red = xt + 64;                 // 1024 f4
  float2* snd2 = (float2*)(red + 1024);  // 256 f4

  int tid = threadIdx.x;
  int j = tid & 255;
  int split = tid >> 8;
  int wv = tid >> 6;
  int lane = tid & 63;
  int jbase = (wv & 3) * 64;
  int bbase = blockIdx.x * 2;
  float4* sb = stage + wv * 512;
  int km = *kmaxp;                       // uniform; multiple of 16
  int G = km >> 4;                       // groups per split (4 entries/group)
  const float4* Pb = PC4 + (size_t)(split * (km >> 3)) * NN + jbase + lane;

  if (tid < 512) {
    int b = tid >> 8, i = tid & 255;
    ((float*)vA2)[i * 2 + b] = state[(bbase + b) * NN + i];
  } else if (tid < 768) {
    int t = tid - 512, b = t >> 7, s = t & 127;
    ((float*)xt)[(s >> 1) * 4 + (s & 1) * 2 + b] = x[(bbase + b) * SS + s];
  }
  __syncthreads();

  // ---- sensory aggregation (dense; compiler-managed loads/waits) ----
  {
    float n0 = 0, n1 = 0, d0 = 0, d1 = 0;
    const float4* Sp = SQ + split * 16 * NN + j;
    const float4* xq = xt + split * 16;
#pragma unroll
    for (int c = 0; c < 16; ++c) { float4 pq = Sp[c * NN]; float4 vv = xq[c]; GATE4(pq, vv); }
    red[split * 256 + j] = make_float4(n0, n1, d0, d1);
    __syncthreads();
    if (split < 2) {
      float n = 0, dd = 0;
#pragma unroll
      for (int k = 0; k < 4; ++k) {
        float4 r = red[k * 256 + j];
        n += split ? r.y : r.x; dd += split ? r.w : r.z;
      }
      snd2[split * 256 + j] = make_float2(n, dd);
    }
    __syncthreads();
  }

  float cmt = cap[j] * (float)UNFOLDS;
  float glv = gl[j];
  float base_ = glv * rp[j];

  // ---- 6 unfolds, one continuous DMA stream ----
  for (int u = 0; u < UNFOLDS; ++u) {
    const float2* vt2 = (u & 1) ? vB2 : vA2;
    float* vnf = (float*)((u & 1) ? vA2 : vB2);
    float n0 = 0, n1 = 0, d0 = 0, d1 = 0;
    int sb0 = (u * G) & 3;                 // global slot base for this unfold

    auto body = [&](int g) {
      const float4* ps = sb + (((sb0 + g) & 3) * 128);
      float4 pq0 = ps[lane];
      float4 pq1 = ps[64 + lane];
      float2 va0 = vt2[__float_as_uint(pq0.y) & 0xFF];
      float2 va1 = vt2[__float_as_uint(pq0.w) & 0xFF];
      float2 va2 = vt2[__float_as_uint(pq1.y) & 0xFF];
      float2 va3 = vt2[__float_as_uint(pq1.w) & 0xFF];
      GATEE(pq0.x, pq0.y, va0);
      GATEE(pq0.z, pq0.w, va1);
      GATEE(pq1.x, pq1.y, va2);
      GATEE(pq1.z, pq1.w, va3);
    };
    // issue group with unfold-local index wrap; slot continues the global ring
    auto issue = [&](int g) {
      int gi = g + 4; if (gi >= G) gi -= G;       // next unfold reuses same addrs
      int slot = (sb0 + g) & 3;                   // == (q+4)&3
      gll16(Pb + (2 * gi + 0) * NN, sb + (slot * 2 + 0) * 64);
      gll16(Pb + (2 * gi + 1) * NN, sb + (slot * 2 + 1) * 64);
    };

    if (u == 0) {   // one-time prologue: groups 0..3 into slots 0..3
      for (int g = 0; g < 4; ++g) {
        gll16(Pb + (2 * g + 0) * NN, sb + (g * 2 + 0) * 64);
        gll16(Pb + (2 * g + 1) * NN, sb + (g * 2 + 1) * 64);
      }
    }

    if (u < UNFOLDS - 1) {
      for (int g = 0; g < G; ++g) {
        asm volatile("s_waitcnt vmcnt(6)" ::: "memory");
        body(g);
        issue(g);                                  // crosses into next unfold
      }
    } else {
      for (int g = 0; g < G - 4; ++g) {
        asm volatile("s_waitcnt vmcnt(6)" ::: "memory");
        body(g);
        issue(g);
      }
      asm volatile("s_waitcnt vmcnt(6)" ::: "memory"); body(G - 4);
      asm volatile("s_waitcnt vmcnt(4)" ::: "memory"); body(G - 3);
      asm volatile("s_waitcnt vmcnt(2)" ::: "memory"); body(G - 2);
      asm volatile("s_waitcnt vmcnt(0)" ::: "memory"); body(G - 1);
    }

    red[split * 256 + j] = make_float4(n0, n1, d0, d1);
    asm volatile("s_waitcnt lgkmcnt(0)" ::: "memory");   // LDS visibility only
    __builtin_amdgcn_s_barrier();                        // DMA stays in flight
    if (split < 2) {
      int b = split;
      float2 sj = snd2[b * 256 + j];
      float N = sj.x, D = sj.y;
#pragma unroll
      for (int k = 0; k < 4; ++k) {
        float4 r = red[k * 256 + j];
        N += b ? r.y : r.x; D += b ? r.w : r.z;
      }
      float2 vj2 = ((const float2*)vt2)[j];
      float vj = b ? vj2.y : vj2.x;
      float vn = (fmaf(cmt, vj, base_) + N) * __builtin_amdgcn_rcpf(cmt + glv + D + EPS_);
      vnf[j * 2 + b] = vn;
      if (u == UNFOLDS - 1) {
        out[BB * MM + (bbase + b) * NN + j] = vn;
        if (j < MM) out[(bbase + b) * MM + j] = fmaf(vn, ow[j], ob[j]);
      }
    }
    asm volatile("s_waitcnt lgkmcnt(0)" ::: "memory");
    __builtin_amdgcn_s_barrier();
  }
}

extern "C" void kernel_launch(void* const* d_in, const int* in_sizes, int n_in,
                              void* d_out, int out_size, void* d_ws, size_t ws_size,
                              hipStream_t stream) {
  const float* x     = (const float*)d_in[0];
  const float* state = (const float*)d_in[1];
  const float* gl    = (const float*)d_in[2];
  const float* rp    = (const float*)d_in[3];
  const float* cap   = (const float*)d_in[4];
  const float* w     = (const float*)d_in[5];
  const float* sg    = (const float*)d_in[6];
  const float* mu    = (const float*)d_in[7];
  const float* E     = (const float*)d_in[8];
  const float* sw    = (const float*)d_in[9];
  const float* ssg   = (const float*)d_in[10];
  const float* smu   = (const float*)d_in[11];
  const float* sE    = (const float*)d_in[12];
  const float* mask  = (const float*)d_in[13];
  const float* smask = (const float*)d_in[14];
  const float* iw    = (const float*)d_in[15];
  const float* ib    = (const float*)d_in[16];
  const float* ow    = (const float*)d_in[17];
  const float* ob    = (const float*)d_in[18];

  float4* PC4 = (float4*)d_ws;                 // [128][NN] f4 = 512 KiB
  float4* SQ  = PC4 + 128 * NN;                // [SS/2][NN] f4 = 256 KiB
  int* cnt    = (int*)(SQ + (SS / 2) * NN);    // 256 ints
  int* kmax   = cnt + 256;
  float* fout = (float*)d_out;                 // [B*M out][B*N v]

  // LDS: stage 8192 + v 256 + xt 64 + red 1024 + snd2 256 = 9792 f4
  const int smem = 9792 * 16;                  // 156672 B <= 163840 B
  hipFuncSetAttribute((const void*)ltc_sparse,
                      hipFuncAttributeMaxDynamicSharedMemorySize, smem);

  prep_compact<<<256 + (SS * NN) / 256, 256, 0, stream>>>(
      w, sg, mu, E, mask, sw, ssg, smu, sE, smask, iw, ib,
      (float2*)PC4, cnt, SQ);
  prep_kmax<<<1, 256, 0, stream>>>(cnt, kmax);
  ltc_sparse<<<BB / 2, 1024, smem, stream>>>(
      x, state, gl, rp, cap, ow, ob, PC4, SQ, kmax, fout);
}